// Round 1
// baseline (30.676 us; speedup 1.0000x reference)
//
#include <hip/hip_runtime.h>
#include <math.h>

#define N_Q 2048
#define M_K 1024
#define DIN 128
#define DK  64

// ---------------------------------------------------------------------------
// Kernel 1: Qp = q @ W^T  (row-major [N_Q][DK]),  KpT = (k @ W^T)^T  ([DK][M_K]),
//           qn2[n] = ||Qp[n]||^2,  kn2[m] = ||Kp[m]||^2
// One wave per row; W staged in LDS (pad +1 -> only 2-way bank alias, free).
// ---------------------------------------------------------------------------
__global__ __launch_bounds__(256) void proj_kernel(
    const float* __restrict__ q, const float* __restrict__ k,
    const float* __restrict__ W, float* __restrict__ Qp,
    float* __restrict__ KpT, float* __restrict__ qn2, float* __restrict__ kn2)
{
    __shared__ float W_lds[DK][DIN + 1];
    __shared__ float row_lds[4][DIN];
    const int tx = threadIdx.x;

    // cooperative load W: 64*128 = 8192 floats, 8 float4 per thread
    const float4* W4 = (const float4*)W;
    #pragma unroll
    for (int i = 0; i < (DK * DIN / 4) / 256; ++i) {
        int idx = tx + i * 256;
        float4 v = W4[idx];
        int base = idx * 4;
        int r = base >> 7, c = base & 127;
        W_lds[r][c]     = v.x;
        W_lds[r][c + 1] = v.y;
        W_lds[r][c + 2] = v.z;
        W_lds[r][c + 3] = v.w;
    }

    const int wave = tx >> 6, lane = tx & 63;
    const int row  = blockIdx.x * 4 + wave;            // 0..3071
    const float* src = (row < N_Q) ? (q + (size_t)row * DIN)
                                   : (k + (size_t)(row - N_Q) * DIN);
    row_lds[wave][lane]      = src[lane];
    row_lds[wave][lane + 64] = src[lane + 64];
    __syncthreads();

    float acc = 0.f;
    #pragma unroll
    for (int d = 0; d < DIN; ++d)
        acc = fmaf(row_lds[wave][d], W_lds[lane][d], acc);

    // wave-reduce sum of squares -> norm^2 of the projected row
    float sq = acc * acc;
    #pragma unroll
    for (int off = 32; off >= 1; off >>= 1)
        sq += __shfl_xor(sq, off, 64);

    if (row < N_Q) {
        Qp[(size_t)row * DK + lane] = acc;
        if (lane == 0) qn2[row] = sq;
    } else {
        const int m = row - N_Q;
        KpT[(size_t)lane * M_K + m] = acc;
        if (lane == 0) kn2[m] = sq;
    }
}

// ---------------------------------------------------------------------------
// Kernel 2: per block -> 8 q-rows x all 1024 m.
// Thread tx owns m = 4*tx .. 4*tx+3 (float4-coalesced KpT loads + out stores).
// acc[8][4] register tile; Qp staged d-major in LDS (broadcast b128 reads).
// Fused: dist^2 -> score -> row softmax (shuffle + LDS block reduce).
// ---------------------------------------------------------------------------
__global__ __launch_bounds__(256) void score_kernel(
    const float* __restrict__ Qp, const float* __restrict__ KpT,
    const float* __restrict__ qn2, const float* __restrict__ kn2,
    float* __restrict__ out)
{
    __shared__ float qpT[DK][8];          // d-major: 8 row-values contiguous per d
    __shared__ float qn2s[8];
    __shared__ float redmax[8][4];
    __shared__ float redsum[8][4];

    const int tx = threadIdx.x;
    const int n0 = blockIdx.x * 8;

    for (int i = tx; i < 8 * DK; i += 256) {
        int r = i & 7, d = i >> 3;
        qpT[d][r] = Qp[(size_t)(n0 + r) * DK + d];
    }
    if (tx < 8) qn2s[tx] = qn2[n0 + tx];
    __syncthreads();

    float acc[8][4];
    #pragma unroll
    for (int r = 0; r < 8; ++r)
        #pragma unroll
        for (int i = 0; i < 4; ++i) acc[r][i] = 0.f;

    const float4* K4 = (const float4*)KpT;
    #pragma unroll 8
    for (int d = 0; d < DK; ++d) {
        float4 kv = K4[d * (M_K / 4) + tx];
        float4 qa = *(const float4*)&qpT[d][0];
        float4 qb = *(const float4*)&qpT[d][4];
        float qv[8]  = {qa.x, qa.y, qa.z, qa.w, qb.x, qb.y, qb.z, qb.w};
        float kvv[4] = {kv.x, kv.y, kv.z, kv.w};
        #pragma unroll
        for (int r = 0; r < 8; ++r)
            #pragma unroll
            for (int i = 0; i < 4; ++i)
                acc[r][i] = fmaf(qv[r], kvv[i], acc[r][i]);
    }

    // scores: s = -0.5*sqrt(max(qn2 + kn2 - 2*dot, 0)), computed in place
    float4 kv2 = ((const float4*)kn2)[tx];
    float kn2a[4] = {kv2.x, kv2.y, kv2.z, kv2.w};
    #pragma unroll
    for (int r = 0; r < 8; ++r) {
        float qn = qn2s[r];
        #pragma unroll
        for (int i = 0; i < 4; ++i) {
            float d2 = fmaxf(fmaf(-2.f, acc[r][i], qn + kn2a[i]), 0.f);
            acc[r][i] = -0.5f * sqrtf(d2);
        }
    }

    const int wave = tx >> 6, lane = tx & 63;

    // block-wide row max
    #pragma unroll
    for (int r = 0; r < 8; ++r) {
        float m = fmaxf(fmaxf(acc[r][0], acc[r][1]), fmaxf(acc[r][2], acc[r][3]));
        #pragma unroll
        for (int off = 32; off >= 1; off >>= 1)
            m = fmaxf(m, __shfl_xor(m, off, 64));
        if (lane == 0) redmax[r][wave] = m;
    }
    __syncthreads();

    float mx[8];
    #pragma unroll
    for (int r = 0; r < 8; ++r)
        mx[r] = fmaxf(fmaxf(redmax[r][0], redmax[r][1]),
                      fmaxf(redmax[r][2], redmax[r][3]));

    // exp + block-wide row sum
    #pragma unroll
    for (int r = 0; r < 8; ++r) {
        float t = 0.f;
        #pragma unroll
        for (int i = 0; i < 4; ++i) {
            acc[r][i] = __expf(acc[r][i] - mx[r]);
            t += acc[r][i];
        }
        #pragma unroll
        for (int off = 32; off >= 1; off >>= 1)
            t += __shfl_xor(t, off, 64);
        if (lane == 0) redsum[r][wave] = t;
    }
    __syncthreads();

    #pragma unroll
    for (int r = 0; r < 8; ++r) {
        float total = redsum[r][0] + redsum[r][1] + redsum[r][2] + redsum[r][3];
        float inv = 1.0f / total;
        float4 o = make_float4(acc[r][0] * inv, acc[r][1] * inv,
                               acc[r][2] * inv, acc[r][3] * inv);
        ((float4*)out)[(size_t)(n0 + r) * (M_K / 4) + tx] = o;
    }
}

extern "C" void kernel_launch(void* const* d_in, const int* in_sizes, int n_in,
                              void* d_out, int out_size, void* d_ws, size_t ws_size,
                              hipStream_t stream)
{
    const float* q = (const float*)d_in[0];
    const float* k = (const float*)d_in[1];
    const float* W = (const float*)d_in[2];
    float* out = (float*)d_out;

    // ws layout (floats): Qp[2048*64] | KpT[64*1024] | qn2[2048] | kn2[1024]
    float* Qp  = (float*)d_ws;
    float* KpT = Qp + (size_t)N_Q * DK;
    float* qn2 = KpT + (size_t)DK * M_K;
    float* kn2 = qn2 + N_Q;

    proj_kernel<<<(N_Q + M_K) / 4, 256, 0, stream>>>(q, k, W, Qp, KpT, qn2, kn2);
    score_kernel<<<N_Q / 8, 256, 0, stream>>>(Qp, KpT, qn2, kn2, out);
}

// Round 2
// 22.966 us; speedup vs baseline: 1.3357x; 1.3357x over previous
//
#include <hip/hip_runtime.h>
#include <math.h>

#define N_Q 2048
#define M_K 1024
#define DIN 128
#define DK  64

// ---------------------------------------------------------------------------
// Kernel 1: Qp = q @ W^T  (row-major [N_Q][DK]),  KpT = (k @ W^T)^T  ([DK][M_K]),
//           qn2[n] = ||Qp[n]||^2,  kn2[m] = ||Kp[m]||^2
// One wave per row. W staged in LDS, stride DIN+4 floats -> conflict-free b128.
// ---------------------------------------------------------------------------
__global__ __launch_bounds__(256) void proj_kernel(
    const float* __restrict__ q, const float* __restrict__ k,
    const float* __restrict__ W, float* __restrict__ Qp,
    float* __restrict__ KpT, float* __restrict__ qn2, float* __restrict__ kn2)
{
    __shared__ float W_lds[DK][DIN + 4];   // stride 132: b128 conflict-free
    __shared__ float row_lds[4][DIN];
    const int tx = threadIdx.x;

    // cooperative load W: 2048 float4s, 8 per thread
    const float4* W4 = (const float4*)W;
    #pragma unroll
    for (int i = 0; i < 8; ++i) {
        int idx = tx + i * 256;            // float4 index
        float4 v = W4[idx];
        int r = idx >> 5, c = (idx & 31) * 4;
        *(float4*)&W_lds[r][c] = v;
    }

    const int wave = tx >> 6, lane = tx & 63;
    const int row  = blockIdx.x * 4 + wave;            // 0..3071
    const float* src = (row < N_Q) ? (q + (size_t)row * DIN)
                                   : (k + (size_t)(row - N_Q) * DIN);
    row_lds[wave][lane]      = src[lane];
    row_lds[wave][lane + 64] = src[lane + 64];
    __syncthreads();

    float acc = 0.f;
    #pragma unroll
    for (int d = 0; d < DIN; d += 4) {
        float4 wv = *(const float4*)&W_lds[lane][d];
        float4 rv = *(const float4*)&row_lds[wave][d];
        acc = fmaf(wv.x, rv.x, acc);
        acc = fmaf(wv.y, rv.y, acc);
        acc = fmaf(wv.z, rv.z, acc);
        acc = fmaf(wv.w, rv.w, acc);
    }

    // wave-reduce sum of squares -> norm^2 of the projected row
    float sq = acc * acc;
    #pragma unroll
    for (int off = 32; off >= 1; off >>= 1)
        sq += __shfl_xor(sq, off, 64);

    if (row < N_Q) {
        Qp[(size_t)row * DK + lane] = acc;
        if (lane == 0) qn2[row] = sq;
    } else {
        const int m = row - N_Q;
        KpT[(size_t)lane * M_K + m] = acc;
        if (lane == 0) kn2[m] = sq;
    }
}

// ---------------------------------------------------------------------------
// Kernel 2: 256 blocks x 512 threads (8 waves -> 2 waves/SIMD at 1 block/CU).
// Block owns 8 q-rows x all 1024 m. Thread tx owns cols {2tx, 2tx+1}, all 8
// rows -> acc[8][2]. No intra-block KpT redundancy (256 KB/block through L1).
// qpT staged d-major in LDS, read as two broadcast b128 per d.
// Fused: dist^2 -> score -> row softmax (shuffle + LDS block reduce).
// ---------------------------------------------------------------------------
__global__ __launch_bounds__(512) void score_kernel(
    const float* __restrict__ Qp, const float* __restrict__ KpT,
    const float* __restrict__ qn2, const float* __restrict__ kn2,
    float* __restrict__ out)
{
    __shared__ float qpT[DK][8];          // d-major: 8 row-values per d
    __shared__ float qn2s[8];
    __shared__ float redmax[8][8];
    __shared__ float redsum[8][8];

    const int tx = threadIdx.x;
    const int n0 = blockIdx.x * 8;
    const int wave = tx >> 6, lane = tx & 63;

    {   // stage Qp^T (2 KB): one element per thread
        int r = tx & 7, d = tx >> 3;
        qpT[d][r] = Qp[(size_t)(n0 + r) * DK + d];
        if (tx < 8) qn2s[tx] = qn2[n0 + tx];
    }
    __syncthreads();

    float acc[8][2];
    #pragma unroll
    for (int r = 0; r < 8; ++r) { acc[r][0] = 0.f; acc[r][1] = 0.f; }

    const float2* K2 = (const float2*)KpT;
    #pragma unroll 8
    for (int d = 0; d < DK; ++d) {
        float2 kv = K2[d * (M_K / 2) + tx];
        float4 qa = *(const float4*)&qpT[d][0];
        float4 qb = *(const float4*)&qpT[d][4];
        float qv[8] = {qa.x, qa.y, qa.z, qa.w, qb.x, qb.y, qb.z, qb.w};
        #pragma unroll
        for (int r = 0; r < 8; ++r) {
            acc[r][0] = fmaf(qv[r], kv.x, acc[r][0]);
            acc[r][1] = fmaf(qv[r], kv.y, acc[r][1]);
        }
    }

    // scores: s = -0.5*sqrt(max(qn2 + kn2 - 2*dot, 0))
    float2 kv2 = ((const float2*)kn2)[tx];
    float kn2a[2] = {kv2.x, kv2.y};
    #pragma unroll
    for (int r = 0; r < 8; ++r) {
        float qn = qn2s[r];
        #pragma unroll
        for (int i = 0; i < 2; ++i) {
            float d2 = fmaxf(fmaf(-2.f, acc[r][i], qn + kn2a[i]), 0.f);
            acc[r][i] = -0.5f * sqrtf(d2);
        }
    }

    // block-wide row max (8 waves -> 8 partials per row)
    #pragma unroll
    for (int r = 0; r < 8; ++r) {
        float m = fmaxf(acc[r][0], acc[r][1]);
        #pragma unroll
        for (int off = 32; off >= 1; off >>= 1)
            m = fmaxf(m, __shfl_xor(m, off, 64));
        if (lane == 0) redmax[r][wave] = m;
    }
    __syncthreads();

    float mx[8];
    #pragma unroll
    for (int r = 0; r < 8; ++r) {
        float4 a = *(const float4*)&redmax[r][0];
        float4 b = *(const float4*)&redmax[r][4];
        mx[r] = fmaxf(fmaxf(fmaxf(a.x, a.y), fmaxf(a.z, a.w)),
                      fmaxf(fmaxf(b.x, b.y), fmaxf(b.z, b.w)));
    }

    // exp + block-wide row sum
    #pragma unroll
    for (int r = 0; r < 8; ++r) {
        acc[r][0] = __expf(acc[r][0] - mx[r]);
        acc[r][1] = __expf(acc[r][1] - mx[r]);
        float t = acc[r][0] + acc[r][1];
        #pragma unroll
        for (int off = 32; off >= 1; off >>= 1)
            t += __shfl_xor(t, off, 64);
        if (lane == 0) redsum[r][wave] = t;
    }
    __syncthreads();

    #pragma unroll
    for (int r = 0; r < 8; ++r) {
        float4 a = *(const float4*)&redsum[r][0];
        float4 b = *(const float4*)&redsum[r][4];
        float total = (a.x + a.y + a.z + a.w) + (b.x + b.y + b.z + b.w);
        float inv = 1.0f / total;
        float2 o = make_float2(acc[r][0] * inv, acc[r][1] * inv);
        ((float2*)out)[(size_t)(n0 + r) * (M_K / 2) + tx] = o;
    }
}

extern "C" void kernel_launch(void* const* d_in, const int* in_sizes, int n_in,
                              void* d_out, int out_size, void* d_ws, size_t ws_size,
                              hipStream_t stream)
{
    const float* q = (const float*)d_in[0];
    const float* k = (const float*)d_in[1];
    const float* W = (const float*)d_in[2];
    float* out = (float*)d_out;

    // ws layout (floats): Qp[2048*64] | KpT[64*1024] | qn2[2048] | kn2[1024]
    float* Qp  = (float*)d_ws;
    float* KpT = Qp + (size_t)N_Q * DK;
    float* qn2 = KpT + (size_t)DK * M_K;
    float* kn2 = qn2 + N_Q;

    proj_kernel<<<(N_Q + M_K) / 4, 256, 0, stream>>>(q, k, W, Qp, KpT, qn2, kn2);
    score_kernel<<<N_Q / 8, 512, 0, stream>>>(Qp, KpT, qn2, kn2, out);
}